// Round 7
// baseline (256.461 us; speedup 1.0000x reference)
//
#include <hip/hip_runtime.h>
#include <hip/hip_bf16.h>
#include <math.h>

// B=4, T=2048, C=1024, H=16, D=64, M = B*T = 8192

typedef short bf16x8 __attribute__((ext_vector_type(8)));
typedef float f32x4 __attribute__((ext_vector_type(4)));
typedef _Float16 f16x4 __attribute__((ext_vector_type(4)));

__device__ __forceinline__ short f2b(float f) {
    unsigned u = __float_as_uint(f);
    u = (u + 0x7fffu + ((u >> 16) & 1u)) >> 16;
    return (short)u;
}

// ---------------------------------------------------------------- cast x
__global__ __launch_bounds__(256) void cast_x_kernel(const float* __restrict__ x,
                                                     short* __restrict__ xb, int n4) {
    int idx = blockIdx.x * 256 + threadIdx.x;
    if (idx >= n4) return;
    float4 v = ((const float4*)x)[idx];
    short4 o;
    o.x = f2b(v.x); o.y = f2b(v.y); o.z = f2b(v.z); o.w = f2b(v.w);
    ((short4*)xb)[idx] = o;
}

// ------------------------------------------- cast + transpose weights (fp32 [K][N] -> bf16 [N][K])
__global__ __launch_bounds__(256) void wtrans_kernel(const float* W0, const float* W1,
                                                     const float* W2, const float* W3,
                                                     short* O0, short* O1, short* O2, short* O3) {
    const float* W; short* O;
    switch (blockIdx.z) {
        case 0: W = W0; O = O0; break;
        case 1: W = W1; O = O1; break;
        case 2: W = W2; O = O2; break;
        default: W = W3; O = O3; break;
    }
    __shared__ __align__(16) float Ls[64 * 68];
    int tid = threadIdx.x;
    int n0 = blockIdx.x * 64, k0 = blockIdx.y * 64;
    #pragma unroll
    for (int it = 0; it < 4; ++it) {
        int c = tid + it * 256;
        int r = c >> 4, off = (c & 15) * 4;
        *(float4*)&Ls[r * 68 + off] = *(const float4*)&W[(k0 + r) * 1024 + n0 + off];
    }
    __syncthreads();
    #pragma unroll
    for (int it = 0; it < 2; ++it) {
        int c = tid + it * 256;
        int n = c >> 3, koff = (c & 7) * 8;
        union { short s[8]; int4 v; } u;
        #pragma unroll
        for (int k = 0; k < 8; ++k) u.s[k] = f2b(Ls[(koff + k) * 68 + n]);
        *(int4*)&O[(n0 + n) * 1024 + k0 + koff] = u.v;
    }
}

// ---------------------------------------------------------------- GEMM 128x128, BK=64 (m97 structure)
// MODE 0: z=0/1 -> bf16 scatter [B,H,T,D] (scaled); z=2 -> f16 V^T [bh][d][t] (fused vtrans)
// MODE 1: fp32 row-major [M][1024]
template<int MODE>
__global__ __launch_bounds__(256) void gemm_kernel(const short* __restrict__ A,
                                                   const short* Bt0, const short* Bt1, const short* Bt2,
                                                   const float* b0, const float* b1, const float* b2,
                                                   float s0, float s1, float s2,
                                                   void* O0, void* O1, void* O2) {
    int z = blockIdx.z;
    const short* Bt   = (z == 0) ? Bt0 : (z == 1) ? Bt1 : Bt2;
    const float* bias = (z == 0) ? b0  : (z == 1) ? b1  : b2;
    float scl         = (z == 0) ? s0  : (z == 1) ? s1  : s2;
    void* Out         = (z == 0) ? O0  : (z == 1) ? O1  : O2;

    __shared__ __align__(16) short As[128 * 64];
    __shared__ __align__(16) short Bs[128 * 64];

    int tid = threadIdx.x;
    int w = tid >> 6, lane = tid & 63, quad = lane >> 4, l15 = lane & 15;
    int m0 = blockIdx.x * 128, n0 = blockIdx.y * 128;
    int wm = (w >> 1) * 64, wn = (w & 1) * 64;
    int lrow = lane >> 3, lcol = (lane & 7) * 8;

    f32x4 acc[4][4] = {};

    for (int kt = 0; kt < 16; ++kt) {
        int k0 = kt * 64;
        __syncthreads();
        #pragma unroll
        for (int it = 0; it < 4; ++it) {
            int r0 = it * 32 + w * 8;
            __builtin_amdgcn_global_load_lds(
                (const __attribute__((address_space(1))) unsigned int*)&A[(m0 + r0 + lrow) * 1024 + k0 + lcol],
                (__attribute__((address_space(3))) unsigned int*)&As[r0 * 64], 16, 0, 0);
            __builtin_amdgcn_global_load_lds(
                (const __attribute__((address_space(1))) unsigned int*)&Bt[(n0 + r0 + lrow) * 1024 + k0 + lcol],
                (__attribute__((address_space(3))) unsigned int*)&Bs[r0 * 64], 16, 0, 0);
        }
        __syncthreads();
        #pragma unroll
        for (int kk = 0; kk < 2; ++kk) {
            bf16x8 af[4], bf[4];
            #pragma unroll
            for (int i = 0; i < 4; ++i)
                af[i] = *(const bf16x8*)&As[(wm + i * 16 + l15) * 64 + kk * 32 + quad * 8];
            #pragma unroll
            for (int j = 0; j < 4; ++j)
                bf[j] = *(const bf16x8*)&Bs[(wn + j * 16 + l15) * 64 + kk * 32 + quad * 8];
            #pragma unroll
            for (int i = 0; i < 4; ++i)
                #pragma unroll
                for (int j = 0; j < 4; ++j)
                    acc[i][j] = __builtin_amdgcn_mfma_f32_16x16x32_bf16(af[i], bf[j], acc[i][j], 0, 0, 0);
        }
    }
    #pragma unroll
    for (int i = 0; i < 4; ++i) {
        #pragma unroll
        for (int j = 0; j < 4; ++j) {
            int gn = n0 + wn + j * 16 + l15;
            float bv = bias[gn];
            if (MODE == 0 && z == 2) {
                // V^T f16 [bh][d][t]: lane owns 4 consecutive t at fixed d -> 8B store
                int h = gn >> 6, d = gn & 63;
                int gm0 = m0 + wm + i * 16 + quad * 4;
                int b = gm0 >> 11, t = gm0 & 2047;
                f16x4 hv;
                #pragma unroll
                for (int r = 0; r < 4; ++r) hv[r] = (_Float16)(acc[i][j][r] + bv);
                *(f16x4*)&((_Float16*)Out)[(((b * 16 + h) * 64) + d) * 2048 + t] = hv;
            } else {
                #pragma unroll
                for (int r = 0; r < 4; ++r) {
                    int gm = m0 + wm + i * 16 + quad * 4 + r;
                    float v = (acc[i][j][r] + bv) * scl;
                    if (MODE == 0) {
                        int b = gm >> 11, t = gm & 2047, h = gn >> 6, d = gn & 63;
                        ((short*)Out)[(((b * 16 + h) * 2048) + t) * 64 + d] = f2b(v);
                    } else {
                        ((float*)Out)[gm * 1024 + gn] = v;
                    }
                }
            }
        }
    }
}

// ---------------------------------------------------------------- flash attention, paired q-tiles
// Q,K bf16 [bh][t][d] (Q pre-scaled by log2(e)/8); Vt f16 [bh][d][t]; Y bf16 [b*T+t][C]
// Block = (bh, p): q-tiles qi_a=p and qi_b=15-p -> exactly 17 compute tile-steps per block,
// 512 blocks = 2/CU, zero tail. K/V staged once per si (shared by both q-tiles).
// S^T = K Q^T (C col=l15=q, row=quad*4+r=s) -> per-lane softmax; p=exp2(s) packed f16 IS the
// 16x16x16f16 B-fragment -> PV straight from registers. XOR-swizzled unpadded LDS (global-side
// swizzle), double-buffered with async prefetch issued before compute (one barrier/step).
__global__ __launch_bounds__(256, 2) void attn_kernel(const short* __restrict__ Q,
                                                      const short* __restrict__ K,
                                                      const _Float16* __restrict__ Vt,
                                                      short* __restrict__ Y) {
    __shared__ __align__(16) short    Ks[2][128 * 64];   // 2 x 16 KB, swizzled
    __shared__ __align__(16) _Float16 Vs[2][64 * 128];   // 2 x 16 KB, swizzled

    int tid = threadIdx.x;
    int w = tid >> 6, lane = tid & 63, quad = lane >> 4, l15 = lane & 15;
    int idx = blockIdx.x;
    int p = idx >> 6;           // 0..7
    int bh = idx & 63;
    int qa = p, qb = 15 - p;    // qb >= 8 > qa always

    const short* Qh = Q + bh * 2048 * 64;
    const short* Kh = K + bh * 2048 * 64;
    const _Float16* Vh = Vt + bh * 64 * 2048;

    // Q fragments for both tiles (B-operand: lane l15 = q, k = quad*8+j)
    bf16x8 qfa[2][2], qfb[2][2];
    #pragma unroll
    for (int i = 0; i < 2; ++i)
        #pragma unroll
        for (int kh = 0; kh < 2; ++kh) {
            int ra = qa * 128 + w * 32 + i * 16 + l15;
            int rb = qb * 128 + w * 32 + i * 16 + l15;
            qfa[i][kh] = *(const bf16x8*)&Qh[ra * 64 + kh * 32 + quad * 8];
            qfb[i][kh] = *(const bf16x8*)&Qh[rb * 64 + kh * 32 + quad * 8];
        }

    // staging address precomputation (global-side XOR swizzle)
    int krow = lane >> 3;
    int kchunk = ((lane & 7) ^ krow) * 8;
    int vrow = lane >> 4;
    int vchunk = ((lane & 15) ^ (w * 4 + vrow)) * 8;
    // swizzled read offsets
    int t7 = l15 & 7;
    int kf0_off = (quad ^ t7) * 8;
    int kf1_off = ((quad + 4) ^ t7) * 8;
    int vsub = (quad & 1) * 4;
    int vchi = quad >> 1;

    f32x4 oa[2][4] = {}, ob[2][4] = {};
    float la[2] = {0.f, 0.f}, lb[2] = {0.f, 0.f};

    auto stage = [&](int s, int bsel) {
        const short* Kt = Kh + s * 128 * 64;
        const _Float16* Vtile = Vh + s * 128;
        short* KsD = &Ks[bsel][0];
        _Float16* VsD = &Vs[bsel][0];
        #pragma unroll
        for (int it = 0; it < 4; ++it) {
            int kr0 = it * 32 + w * 8;
            __builtin_amdgcn_global_load_lds(
                (const __attribute__((address_space(1))) unsigned int*)&Kt[(kr0 + krow) * 64 + kchunk],
                (__attribute__((address_space(3))) unsigned int*)&KsD[kr0 * 64], 16, 0, 0);
            int vr0 = it * 16 + w * 4;
            __builtin_amdgcn_global_load_lds(
                (const __attribute__((address_space(1))) unsigned int*)&Vtile[(vr0 + vrow) * 2048 + vchunk],
                (__attribute__((address_space(3))) unsigned int*)&VsD[vr0 * 128], 16, 0, 0);
        }
    };

    stage(0, 0);
    __syncthreads();   // vmcnt drained by compiler before barrier

    for (int si = 0; si <= qb; ++si) {
        int buf = si & 1;
        if (si < qb) stage(si + 1, buf ^ 1);   // async prefetch; drains at end-of-step barrier

        const short* KsB = &Ks[buf][0];
        const _Float16* VsB = &Vs[buf][0];
        bool do_a = (si <= qa);
        bool diag_a = (si == qa), diag_b = (si == qb);

        #pragma unroll
        for (int j = 0; j < 8; ++j) {
            int trow = (j * 16 + l15) * 64;
            bf16x8 kf0 = *(const bf16x8*)&KsB[trow + kf0_off];
            bf16x8 kf1 = *(const bf16x8*)&KsB[trow + kf1_off];
            int vc = j * 2 + vchi;
            f16x4 vf[4];
            #pragma unroll
            for (int mt = 0; mt < 4; ++mt)
                vf[mt] = *(const f16x4*)&VsB[(mt * 16 + l15) * 128 + ((vc ^ l15) * 8) + vsub];

            // ---- tile b (always active) ----
            #pragma unroll
            for (int i = 0; i < 2; ++i) {
                f32x4 a = {};
                a = __builtin_amdgcn_mfma_f32_16x16x32_bf16(kf0, qfb[i][0], a, 0, 0, 0);
                a = __builtin_amdgcn_mfma_f32_16x16x32_bf16(kf1, qfb[i][1], a, 0, 0, 0);
                if (diag_b) {
                    int qrel = w * 32 + i * 16 + l15;
                    #pragma unroll
                    for (int r = 0; r < 4; ++r)
                        if (j * 16 + quad * 4 + r > qrel) a[r] = -1e30f;
                }
                f16x4 pfv;
                float p0 = __builtin_amdgcn_exp2f(a[0]);
                float p1 = __builtin_amdgcn_exp2f(a[1]);
                float p2 = __builtin_amdgcn_exp2f(a[2]);
                float p3 = __builtin_amdgcn_exp2f(a[3]);
                lb[i] += (p0 + p1) + (p2 + p3);
                pfv[0] = (_Float16)p0; pfv[1] = (_Float16)p1;
                pfv[2] = (_Float16)p2; pfv[3] = (_Float16)p3;
                #pragma unroll
                for (int mt = 0; mt < 4; ++mt)
                    ob[i][mt] = __builtin_amdgcn_mfma_f32_16x16x16f16(vf[mt], pfv, ob[i][mt], 0, 0, 0);
            }
            // ---- tile a (si <= qa; block-uniform branch) ----
            if (do_a) {
                #pragma unroll
                for (int i = 0; i < 2; ++i) {
                    f32x4 a = {};
                    a = __builtin_amdgcn_mfma_f32_16x16x32_bf16(kf0, qfa[i][0], a, 0, 0, 0);
                    a = __builtin_amdgcn_mfma_f32_16x16x32_bf16(kf1, qfa[i][1], a, 0, 0, 0);
                    if (diag_a) {
                        int qrel = w * 32 + i * 16 + l15;
                        #pragma unroll
                        for (int r = 0; r < 4; ++r)
                            if (j * 16 + quad * 4 + r > qrel) a[r] = -1e30f;
                    }
                    f16x4 pfv;
                    float p0 = __builtin_amdgcn_exp2f(a[0]);
                    float p1 = __builtin_amdgcn_exp2f(a[1]);
                    float p2 = __builtin_amdgcn_exp2f(a[2]);
                    float p3 = __builtin_amdgcn_exp2f(a[3]);
                    la[i] += (p0 + p1) + (p2 + p3);
                    pfv[0] = (_Float16)p0; pfv[1] = (_Float16)p1;
                    pfv[2] = (_Float16)p2; pfv[3] = (_Float16)p3;
                    #pragma unroll
                    for (int mt = 0; mt < 4; ++mt)
                        oa[i][mt] = __builtin_amdgcn_mfma_f32_16x16x16f16(vf[mt], pfv, oa[i][mt], 0, 0, 0);
                }
            }
        }
        __syncthreads();   // all waves done reading buf; prefetch (vmcnt) drained
    }

    int b = bh >> 4, h = bh & 15;
    #pragma unroll
    for (int i = 0; i < 2; ++i) {
        // tile a
        float l = la[i];
        l += __shfl_xor(l, 16);
        l += __shfl_xor(l, 32);
        float rinv = 1.0f / l;
        int q = qa * 128 + w * 32 + i * 16 + l15;
        short* yrow = &Y[(b * 2048 + q) * 1024 + h * 64];
        #pragma unroll
        for (int mt = 0; mt < 4; ++mt) {
            short4 s4;
            s4.x = f2b(oa[i][mt][0] * rinv);
            s4.y = f2b(oa[i][mt][1] * rinv);
            s4.z = f2b(oa[i][mt][2] * rinv);
            s4.w = f2b(oa[i][mt][3] * rinv);
            *(short4*)&yrow[mt * 16 + quad * 4] = s4;
        }
        // tile b
        l = lb[i];
        l += __shfl_xor(l, 16);
        l += __shfl_xor(l, 32);
        rinv = 1.0f / l;
        q = qb * 128 + w * 32 + i * 16 + l15;
        yrow = &Y[(b * 2048 + q) * 1024 + h * 64];
        #pragma unroll
        for (int mt = 0; mt < 4; ++mt) {
            short4 s4;
            s4.x = f2b(ob[i][mt][0] * rinv);
            s4.y = f2b(ob[i][mt][1] * rinv);
            s4.z = f2b(ob[i][mt][2] * rinv);
            s4.w = f2b(ob[i][mt][3] * rinv);
            *(short4*)&yrow[mt * 16 + quad * 4] = s4;
        }
    }
}

// ----------------------------------------------------------------
extern "C" void kernel_launch(void* const* d_in, const int* in_sizes, int n_in,
                              void* d_out, int out_size, void* d_ws, size_t ws_size,
                              hipStream_t stream) {
    const float* x  = (const float*)d_in[0];
    const float* Wk = (const float*)d_in[1];
    const float* bk = (const float*)d_in[2];
    const float* Wq = (const float*)d_in[3];
    const float* bq = (const float*)d_in[4];
    const float* Wv = (const float*)d_in[5];
    const float* bv = (const float*)d_in[6];
    const float* Wp = (const float*)d_in[7];
    const float* bp = (const float*)d_in[8];

    char* ws = (char*)d_ws;
    short*     xb  = (short*)(ws + 0);          // 16 MB  x bf16 [8192][1024]
    short*     Wqt = (short*)(ws + 16777216);   // 2 MB each, bf16 [N][K]
    short*     Wkt = (short*)(ws + 18874368);
    short*     Wvt = (short*)(ws + 20971520);
    short*     Wpt = (short*)(ws + 23068672);
    short*     Qb  = (short*)(ws + 25165824);   // 16 MB [B,H,T,D] (pre-scaled by log2e/8)
    short*     Kb  = (short*)(ws + 41943040);   // 16 MB [B,H,T,D]
    _Float16*  Vtb = (_Float16*)(ws + 75497472);// 16 MB [B,H,D,T] f16 (written by fused GEMM)
    short*     Yb  = (short*)(ws + 92274688);   // 16 MB [B*T][C]

    cast_x_kernel<<<8192, 256, 0, stream>>>(x, xb, 2097152);
    wtrans_kernel<<<dim3(16, 16, 4), 256, 0, stream>>>(Wq, Wk, Wv, Wp, Wqt, Wkt, Wvt, Wpt);
    gemm_kernel<0><<<dim3(64, 8, 3), 256, 0, stream>>>(xb, Wqt, Wkt, Wvt, bq, bk, bv,
                                                       0.18033688011112042f /* log2e/8 */, 1.0f, 1.0f,
                                                       (void*)Qb, (void*)Kb, (void*)Vtb);
    attn_kernel<<<512, 256, 0, stream>>>(Qb, Kb, Vtb, Yb);
    gemm_kernel<1><<<dim3(64, 8, 1), 256, 0, stream>>>(Yb, Wpt, nullptr, nullptr,
                                                       bp, nullptr, nullptr,
                                                       1.0f, 1.0f, 1.0f,
                                                       (void*)d_out, nullptr, nullptr);
}